// Round 2
// baseline (664.892 us; speedup 1.0000x reference)
//
#include <hip/hip_runtime.h>

// ============================================================================
// GNN_22170621182157 R6: 8-wave GEMM blocks (2 waves/SIMD) for stall overlap.
//   i8 4-term core: 128x128 tile, BK=64, now 8 waves (2M x 4N), per-wave
//   64x32 out -> acc 96 regs (was 192) -> 2 waves/SIMD instead of 1.
//   Same LDS layout, same dbuf + raw-barrier + counted-vmcnt structure.
//   f16 core identically restructured (acc 32 regs).
//
// Math (softmax row-shift invariance):
//   softmax(adj) == softmax( S F^T + 1*c^T ), S = F Mt^T, Mt = Wk Wq^T,
//   c = F (Wk bq);  out = P (F Wu) + bu.
// Fixed-point: x ~ r/s, r = a1*256 + a0 (i8 digits).  s_F=s_S=5440,
// s_W=s_Mt=261120.  comb = 65536*hh + 256*(a1b0+a0b1) + a0b0 (all i32 exact).
// ============================================================================

typedef unsigned short u16;
typedef unsigned int   u32;
typedef signed char    i8;
typedef _Float16 f16;
typedef f16    f16x8 __attribute__((ext_vector_type(8)));
typedef float  f32x4 __attribute__((ext_vector_type(4)));
typedef int    i32x4 __attribute__((ext_vector_type(4)));
typedef u32    u32x4 __attribute__((ext_vector_type(4)));
typedef u16    u16x4 __attribute__((ext_vector_type(4)));

#define WAIT_VM4   0x0F74  // vmcnt(4), exp 7, lgkm 15
#define WAIT_VM2   0x0F72  // vmcnt(2)
#define WAIT_VM0   0x0F70  // vmcnt(0)
#define WAIT_LGKM0 0xC07F  // lgkmcnt(0), vm 63, exp 7

__device__ __forceinline__ void gload16(const void* g, void* l) {
    __builtin_amdgcn_global_load_lds(
        (const __attribute__((address_space(1))) unsigned int*)g,
        (__attribute__((address_space(3))) unsigned int*)l, 16, 0, 0);
}

__device__ __forceinline__ void tile_swizzle(int& tx, int& ty) {
    const int gx = gridDim.x, gy = gridDim.y;
    const int lin = blockIdx.y * gx + blockIdx.x;
    const int G = 4;
    const int gid = lin / (G * gx);
    const int g0 = gid * G;
    const int gh = min(G, gy - g0);
    const int rem = lin - gid * (G * gx);
    ty = g0 + rem % gh;
    tx = rem / gh;
}

__device__ __forceinline__ void digits256(float v, float s, i8& d1, i8& d0) {
    float f = fminf(fmaxf(v * s, -32600.0f), 32600.0f);
    int r = __float2int_rn(f);
    int a1 = (r + 128) >> 8;
    int a0 = r - (a1 << 8);
    d1 = (i8)a1;
    d0 = (i8)a0;
}

// ---------------------------------------------------------------------------
// i8 merged 4-term GEMM body: C = A @ Bt^T.  128x128 tile, BK=64 B, 8 waves
// (2M x 4N), per-wave 4x2 frags of mfma_i32_16x16x64_i8; acc sets hh/cross/ll
// (96 regs -> 2 waves/SIMD).
// Staging: global_load_lds 16B into unpadded LDS (row=64B), chunk swizzle
// slot=(kq+(row>>1))&3; one 16B chunk per plane per thread (4 loads/tile).
// Double-buffered; raw s_barrier + manual vmcnt(4): next-tile DMA in flight.
// EPI 0: requantize to digit planes.  EPI 1: fp32 out.
// Needs 2*32768 B of LDS at ldsb.  512 threads.
// ---------------------------------------------------------------------------
template <int EPI>
__device__ __forceinline__ void gemm_i8_body(
    i8* ldsb, int tx, int ty, int z,
    const i8* __restrict__ Ah, const i8* __restrict__ Al,
    const i8* __restrict__ Bh, const i8* __restrict__ Bl,
    i8* __restrict__ Qh, i8* __restrict__ Ql, float* __restrict__ Cf,
    float oscale, int N, int K, long strA, long strB, long strC) {
    // planes within one 32 KB buffer: Ah 0, Al 8K, Bh 16K, Bl 24K
    const int tid  = threadIdx.x;
    const int lane = tid & 63;
    const int wv   = tid >> 6;          // 0..7
    const int wm   = wv >> 2, wn = wv & 3;
    const int l16  = lane & 15, kq = lane >> 4;
    const long rowBase = (long)ty * 128;
    const long colBase = (long)tx * 128;

    const i8* pAh = Ah + (long)z * strA;
    const i8* pAl = Al + (long)z * strA;
    const i8* pBh = Bh + (long)z * strB;
    const i8* pBl = Bl + (long)z * strB;

    // ---- staging geometry (per thread: one 16B chunk per plane) ----
    const int l4r = lane >> 2, l4c = lane & 3;
    const int rin = wv * 16 + l4r;                   // row within tile, 0..127
    const int kw  = (l4c - (rin >> 1)) & 3;          // global chunk this lane fetches
    const u32 voffA = (u32)((rowBase + rin) * (long)K) + kw * 16;
    const u32 voffB = (u32)((colBase + rin) * (long)K) + kw * 16;
    const int ldsoff = wv * 16 * 64;                 // wave-uniform dest

    // ---- fragment read offsets (chunk-swizzled) ----
    int aoff[4], boff[2];
    #pragma unroll
    for (int i = 0; i < 4; ++i) {
        const int rA = wm * 64 + i * 16 + l16;
        aoff[i] = rA * 64 + ((kq + (rA >> 1)) & 3) * 16;
    }
    #pragma unroll
    for (int j = 0; j < 2; ++j) {
        const int rB = wn * 32 + j * 16 + l16;
        boff[j] = rB * 64 + ((kq + (rB >> 1)) & 3) * 16;
    }

    const i32x4 izero = {0, 0, 0, 0};
    i32x4 ahh[4][2], acx[4][2], all_[4][2];
    #pragma unroll
    for (int i = 0; i < 4; ++i)
        #pragma unroll
        for (int j = 0; j < 2; ++j) { ahh[i][j] = izero; acx[i][j] = izero; all_[i][j] = izero; }

    const int nk = K >> 6;

    // issue tile 0 -> buf 0
    gload16(pAh + voffA, ldsb         + ldsoff);
    gload16(pAl + voffA, ldsb + 8192  + ldsoff);
    gload16(pBh + voffB, ldsb + 16384 + ldsoff);
    gload16(pBl + voffB, ldsb + 24576 + ldsoff);

    for (int kt = 0; kt < nk; ++kt) {
        const int cur = kt & 1;
        if (kt + 1 < nk) {
            const long ko = (long)(kt + 1) * 64;
            i8* nb = ldsb + (1 - cur) * 32768;
            gload16(pAh + voffA + ko, nb         + ldsoff);
            gload16(pAl + voffA + ko, nb + 8192  + ldsoff);
            gload16(pBh + voffB + ko, nb + 16384 + ldsoff);
            gload16(pBl + voffB + ko, nb + 24576 + ldsoff);
            __builtin_amdgcn_s_waitcnt(WAIT_VM4);   // cur tile landed; next in flight
        } else {
            __builtin_amdgcn_s_waitcnt(WAIT_VM0);
        }
        __builtin_amdgcn_s_barrier();

        const i8* base = ldsb + cur * 32768;
        i32x4 fbh[2], fbl[2];
        #pragma unroll
        for (int j = 0; j < 2; ++j) {
            fbh[j] = *(const i32x4*)(base + 16384 + boff[j]);
            fbl[j] = *(const i32x4*)(base + 24576 + boff[j]);
        }
        #pragma unroll
        for (int i = 0; i < 4; ++i) {
            i32x4 fah = *(const i32x4*)(base + aoff[i]);
            i32x4 fal = *(const i32x4*)(base + 8192 + aoff[i]);
            #pragma unroll
            for (int j = 0; j < 2; ++j) {
                ahh[i][j]  = __builtin_amdgcn_mfma_i32_16x16x64_i8(fah, fbh[j], ahh[i][j], 0, 0, 0);
                acx[i][j]  = __builtin_amdgcn_mfma_i32_16x16x64_i8(fah, fbl[j], acx[i][j], 0, 0, 0);
                acx[i][j]  = __builtin_amdgcn_mfma_i32_16x16x64_i8(fal, fbh[j], acx[i][j], 0, 0, 0);
                all_[i][j] = __builtin_amdgcn_mfma_i32_16x16x64_i8(fal, fbl[j], all_[i][j], 0, 0, 0);
            }
        }
        __builtin_amdgcn_s_waitcnt(WAIT_LGKM0);     // my ds_reads done
        __builtin_amdgcn_s_barrier();               // buffer safe to overwrite
    }

    // epilogue: C/D layout col=lane&15, row=(lane>>4)*4+reg
    #pragma unroll
    for (int i = 0; i < 4; ++i) {
        const long gr0 = rowBase + wm * 64 + i * 16 + kq * 4;
        #pragma unroll
        for (int j = 0; j < 2; ++j) {
            const long gc = colBase + wn * 32 + j * 16 + l16;
            #pragma unroll
            for (int r = 0; r < 4; ++r) {
                const float comb = 65536.0f * (float)ahh[i][j][r] +
                                     256.0f * (float)acx[i][j][r] +
                                             (float)all_[i][j][r];
                const long o = (gr0 + r) * (long)N + gc;
                if constexpr (EPI == 0) {
                    i8 d1, d0;
                    digits256(comb, oscale, d1, d0);
                    Qh[o] = d1;
                    Ql[o] = d0;
                } else {
                    Cf[(long)z * strC + o] = comb * oscale;
                }
            }
        }
    }
}

// ---------------------------------------------------------------------------
// fp16 GEMM body: C = A @ Bt^T, BK=32 (64 B rows - same staging geometry),
// 8 waves (2M x 4N), per-wave 4x2 frags (acc 32 regs).
// EPI 2: fp16 transposed write (vT);  EPI 3: fp32 + bias[col].
// Needs 2*16384 B of LDS at ldsb.  512 threads.
// ---------------------------------------------------------------------------
template <int EPI>
__device__ __forceinline__ void gemm_f16_body(
    i8* ldsb, int tx, int ty, int z,
    const u16* __restrict__ A, const u16* __restrict__ B,
    u16* __restrict__ Ch, float* __restrict__ Cf,
    const float* __restrict__ bias,
    int N, int K, long strA, long strB, long strC) {
    // planes within one 16 KB buffer: A 0, B 8K
    const int tid  = threadIdx.x;
    const int lane = tid & 63;
    const int wv   = tid >> 6;
    const int wm   = wv >> 2, wn = wv & 3;
    const int l16  = lane & 15, kq = lane >> 4;
    const long rowBase = (long)ty * 128;
    const long colBase = (long)tx * 128;

    const u16* pA = A + (long)z * strA;
    const u16* pB = B + (long)z * strB;

    const int l4r = lane >> 2, l4c = lane & 3;
    const int rin = wv * 16 + l4r;
    const int kw  = (l4c - (rin >> 1)) & 3;
    const u32 voffA = (u32)((rowBase + rin) * (long)K) + kw * 8;  // u16 units
    const u32 voffB = (u32)((colBase + rin) * (long)K) + kw * 8;
    const int ldsoff = wv * 16 * 64;                              // bytes

    int aoff[4], boff[2];
    #pragma unroll
    for (int i = 0; i < 4; ++i) {
        const int rA = wm * 64 + i * 16 + l16;
        aoff[i] = rA * 64 + ((kq + (rA >> 1)) & 3) * 16;
    }
    #pragma unroll
    for (int j = 0; j < 2; ++j) {
        const int rB = wn * 32 + j * 16 + l16;
        boff[j] = rB * 64 + ((kq + (rB >> 1)) & 3) * 16;
    }

    const f32x4 vzero = {0.f, 0.f, 0.f, 0.f};
    f32x4 acc[4][2];
    #pragma unroll
    for (int i = 0; i < 4; ++i)
        #pragma unroll
        for (int j = 0; j < 2; ++j) acc[i][j] = vzero;

    const int nk = K >> 5;

    gload16(pA + voffA, ldsb        + ldsoff);
    gload16(pB + voffB, ldsb + 8192 + ldsoff);

    for (int kt = 0; kt < nk; ++kt) {
        const int cur = kt & 1;
        if (kt + 1 < nk) {
            const long ko = (long)(kt + 1) * 32;
            i8* nb = ldsb + (1 - cur) * 16384;
            gload16(pA + voffA + ko, nb        + ldsoff);
            gload16(pB + voffB + ko, nb + 8192 + ldsoff);
            __builtin_amdgcn_s_waitcnt(WAIT_VM2);
        } else {
            __builtin_amdgcn_s_waitcnt(WAIT_VM0);
        }
        __builtin_amdgcn_s_barrier();

        const i8* base = ldsb + cur * 16384;
        f16x8 fa[4];
        #pragma unroll
        for (int i = 0; i < 4; ++i)
            fa[i] = __builtin_bit_cast(f16x8, *(const u32x4*)(base + aoff[i]));
        #pragma unroll
        for (int j = 0; j < 2; ++j) {
            f16x8 fb = __builtin_bit_cast(f16x8, *(const u32x4*)(base + 8192 + boff[j]));
            #pragma unroll
            for (int i = 0; i < 4; ++i)
                acc[i][j] = __builtin_amdgcn_mfma_f32_16x16x32_f16(fa[i], fb, acc[i][j], 0, 0, 0);
        }
        __builtin_amdgcn_s_waitcnt(WAIT_LGKM0);
        __builtin_amdgcn_s_barrier();
    }

    #pragma unroll
    for (int i = 0; i < 4; ++i) {
        const long gr0 = rowBase + wm * 64 + i * 16 + kq * 4;
        #pragma unroll
        for (int j = 0; j < 2; ++j) {
            const long gc = colBase + wn * 32 + j * 16 + l16;
            f32x4 a = acc[i][j];
            if constexpr (EPI == 2) {
                const int b  = (int)(gr0 / 2304);
                const int n0 = (int)(gr0 - (long)b * 2304);
                u16x4 o4;
                #pragma unroll
                for (int r = 0; r < 4; ++r) o4[r] = __builtin_bit_cast(u16, (f16)a[r]);
                *(u16x4*)&Ch[(long)b * (1024L * 2304) + gc * 2304 + n0] = o4;
            } else {
                float* C = Cf + (long)z * strC;
                const float bv = bias[gc];
                #pragma unroll
                for (int r = 0; r < 4; ++r) C[(gr0 + r) * (long)N + gc] = a[r] + bv;
            }
        }
    }
}

// ---------------------------------------------------------------------------
// quantFc body (512 threads): F fp32 -> fp16 + i8 digit planes (scale 5440)
// + c[row] = F[row].u.  red must point to >=8 floats of shared memory.
// ---------------------------------------------------------------------------
__device__ __forceinline__ void quantFc_body(long row, float* red,
                                             const float* __restrict__ F,
                                             const float* __restrict__ u,
                                             u16* __restrict__ F16,
                                             i8* __restrict__ hi,
                                             i8* __restrict__ lo,
                                             float* __restrict__ c) {
    const int tid = threadIdx.x;   // 0..511
    const float* fr = F + row * 2048;
    float dot = 0.f;
    #pragma unroll
    for (int t = 0; t < 4; ++t) {
        const int i = t * 512 + tid;
        const float v = fr[i];
        F16[row * 2048 + i] = __builtin_bit_cast(u16, (f16)v);
        i8 d1, d0;
        digits256(v, 5440.0f, d1, d0);
        hi[row * 2048 + i] = d1;
        lo[row * 2048 + i] = d0;
        dot += v * u[i];
    }
    #pragma unroll
    for (int off = 32; off >= 1; off >>= 1) dot += __shfl_down(dot, off);
    if ((tid & 63) == 0) red[tid >> 6] = dot;
    __syncthreads();
    if (tid == 0) {
        float s = 0.f;
        #pragma unroll
        for (int w = 0; w < 8; ++w) s += red[w];
        c[row] = s;
    }
}

// ---------------------------------------------------------------------------
// prep_k: all independent pre-passes in one launch (256 threads).
//   blocks [0,2048)      : u[row] = Wk[row,:] . bq
//   blocks [2048,4096)   : WuT transpose tile (32x32)
//   blocks [4096,20480)  : quantW(Wq)
//   blocks [20480,36864) : quantW(Wk)
// ---------------------------------------------------------------------------
__global__ __launch_bounds__(256) void prep_k(const float* __restrict__ Wk,
                                              const float* __restrict__ bq,
                                              float* __restrict__ u,
                                              const float* __restrict__ Wq,
                                              i8* __restrict__ Wqh, i8* __restrict__ Wql,
                                              i8* __restrict__ Wkh, i8* __restrict__ Wkl,
                                              const float* __restrict__ Wu,
                                              u16* __restrict__ WuT) {
    __shared__ __align__(16) float sm[32 * 33];
    const int tid = threadIdx.x;
    const int id = blockIdx.x;
    if (id < 2048) {
        // gemv: u[id] = Wk[id,:] . bq
        const float* ar = Wk + (long)id * 2048;
        float s = 0.f;
        #pragma unroll
        for (int t = 0; t < 8; ++t) s += ar[t * 256 + tid] * bq[t * 256 + tid];
        #pragma unroll
        for (int off = 32; off >= 1; off >>= 1) s += __shfl_down(s, off);
        if ((tid & 63) == 0) sm[tid >> 6] = s;
        __syncthreads();
        if (tid == 0) u[id] = sm[0] + sm[1] + sm[2] + sm[3];
    } else if (id < 4096) {
        // WuT: Wu [2048][1024] -> WuT [1024][2048] fp16
        const int w  = id - 2048;
        const int bx = (w & 31) * 32;   // col tile of Wu
        const int by = (w >> 5) * 32;   // row tile of Wu
        const int lx = tid & 31, ly = tid >> 5;
        float (*t)[33] = (float (*)[33])sm;
        #pragma unroll
        for (int dy = 0; dy < 32; dy += 8)
            t[ly + dy][lx] = Wu[(long)(by + ly + dy) * 1024 + bx + lx];
        __syncthreads();
        #pragma unroll
        for (int dy = 0; dy < 32; dy += 8)
            WuT[(long)(bx + ly + dy) * 2048 + by + lx] =
                __builtin_bit_cast(u16, (f16)t[lx][ly + dy]);
    } else {
        long j = (long)id - 4096;       // 0..32767 block-units of 256 elems
        const float* src;
        i8 *dh, *dl;
        if (j < 16384) { src = Wq; dh = Wqh; dl = Wql; }
        else           { j -= 16384; src = Wk; dh = Wkh; dl = Wkl; }
        const long i = j * 256 + tid;   // < 4194304
        i8 d1, d0;
        digits256(src[i], 261120.0f, d1, d0);
        dh[i] = d1;
        dl[i] = d0;
    }
}

// ---------------------------------------------------------------------------
// fused_qfc_mt (512 threads): Mt = Wk @ Wq^T (blocks 0..255, launched first -
// on the critical path to S) packed with quantFc (blocks 256..9471, BW-bound).
// ---------------------------------------------------------------------------
__global__ __launch_bounds__(512, 2) void fused_qfc_mt(
    const float* __restrict__ F, const float* __restrict__ u,
    u16* __restrict__ F16, i8* __restrict__ Fh, i8* __restrict__ Fl,
    float* __restrict__ c,
    const i8* __restrict__ Wqh, const i8* __restrict__ Wql,
    const i8* __restrict__ Wkh, const i8* __restrict__ Wkl,
    i8* __restrict__ Mth, i8* __restrict__ Mtl) {
    __shared__ __align__(16) i8 lds[2][32768];
    const int b = blockIdx.x;
    if (b < 256) {
        gemm_i8_body<0>(&lds[0][0], b & 15, b >> 4, 0,
                        Wkh, Wkl, Wqh, Wql, Mth, Mtl, nullptr,
                        3.8296569e-06f, 2048, 2048, 0L, 0L, 0L);
    } else {
        quantFc_body((long)b - 256, (float*)&lds[0][0], F, u, F16, Fh, Fl, c);
    }
}

// ---------------------------------------------------------------------------
// fused_sv (512 threads): S = F @ Mt^T (bx<16) packed with v = F16 @ WuT^T
// -> vT (bx>=16).  Grid (24, 72).
// ---------------------------------------------------------------------------
__global__ __launch_bounds__(512, 2) void fused_sv(
    const i8* __restrict__ Fh, const i8* __restrict__ Fl,
    const i8* __restrict__ Mth, const i8* __restrict__ Mtl,
    i8* __restrict__ Sh, i8* __restrict__ Sl,
    const u16* __restrict__ F16, const u16* __restrict__ WuT,
    u16* __restrict__ vT) {
    __shared__ __align__(16) i8 lds[2][32768];
    const int bx = blockIdx.x, by = blockIdx.y;
    if (bx < 16) {
        gemm_i8_body<0>(&lds[0][0], bx, by, 0,
                        Fh, Fl, Mth, Mtl, Sh, Sl, nullptr,
                        3.8296569e-06f, 2048, 2048, 0L, 0L, 0L);
    } else {
        gemm_f16_body<2>(&lds[0][0], bx - 16, by, 0,
                         F16, WuT, vT, nullptr, nullptr,
                         1024, 2048, 0L, 0L, 0L);
    }
}

// ---------------------------------------------------------------------------
// Standalone GEMM wrappers (adj and out; keep XCD/L2 tile swizzle).
// ---------------------------------------------------------------------------
template <int EPI>
__global__ __launch_bounds__(512, 2) void gemm_i8_k(
    const i8* __restrict__ Ah, const i8* __restrict__ Al,
    const i8* __restrict__ Bh, const i8* __restrict__ Bl,
    i8* __restrict__ Qh, i8* __restrict__ Ql, float* __restrict__ Cf,
    float oscale, int N, int K, long strA, long strB, long strC) {
    __shared__ __align__(16) i8 lds[2][32768];
    int tx, ty;
    tile_swizzle(tx, ty);
    gemm_i8_body<EPI>(&lds[0][0], tx, ty, blockIdx.z,
                      Ah, Al, Bh, Bl, Qh, Ql, Cf, oscale, N, K, strA, strB, strC);
}

template <int EPI>
__global__ __launch_bounds__(512, 2) void gemm_f16_k(
    const u16* __restrict__ A, const u16* __restrict__ B,
    u16* __restrict__ Ch, float* __restrict__ Cf,
    const float* __restrict__ bias,
    int N, int K, long strA, long strB, long strC) {
    __shared__ __align__(16) i8 lds[2][16384];
    int tx, ty;
    tile_swizzle(tx, ty);
    gemm_f16_body<EPI>(&lds[0][0], tx, ty, blockIdx.z,
                       A, B, Ch, Cf, bias, N, K, strA, strB, strC);
}

// ---------------------------------------------------------------------------
// Row softmax over 2304 cols with per-column bias c[m]; fp32 in, fp16 out.
// ---------------------------------------------------------------------------
__global__ __launch_bounds__(256) void softmax_k(const float* __restrict__ adj,
                                                 const float* __restrict__ c,
                                                 u16* __restrict__ P) {
    const int n = 2304;
    const int row = blockIdx.x, b = blockIdx.y;
    const int tid = threadIdx.x;
    const float* ar = adj + ((long)b * n + row) * (long)n;
    const float* cb = c + (long)b * n;
    u16* pr = P + ((long)b * n + row) * (long)n;

    float v[9];
    float mx = -3.0e38f;
    #pragma unroll
    for (int t = 0; t < 9; ++t) {
        const int i = t * 256 + tid;
        const float x = ar[i] + cb[i];
        v[t] = x;
        mx = fmaxf(mx, x);
    }
    #pragma unroll
    for (int off = 32; off >= 1; off >>= 1) mx = fmaxf(mx, __shfl_down(mx, off));
    __shared__ float red[4];
    if ((tid & 63) == 0) red[tid >> 6] = mx;
    __syncthreads();
    mx = fmaxf(fmaxf(red[0], red[1]), fmaxf(red[2], red[3]));

    float s = 0.f;
    #pragma unroll
    for (int t = 0; t < 9; ++t) {
        const float e = __expf(v[t] - mx);
        v[t] = e;
        s += e;
    }
    #pragma unroll
    for (int off = 32; off >= 1; off >>= 1) s += __shfl_down(s, off);
    __shared__ float red2[4];
    if ((tid & 63) == 0) red2[tid >> 6] = s;
    __syncthreads();
    s = red2[0] + red2[1] + red2[2] + red2[3];
    const float inv = 1.0f / s;
    #pragma unroll
    for (int t = 0; t < 9; ++t)
        pr[t * 256 + tid] = __builtin_bit_cast(u16, (f16)(v[t] * inv));
}

// ---------------------------------------------------------------------------
// Host launch
// ---------------------------------------------------------------------------
extern "C" void kernel_launch(void* const* d_in, const int* in_sizes, int n_in,
                              void* d_out, int out_size, void* d_ws, size_t ws_size,
                              hipStream_t stream) {
    (void)in_sizes; (void)n_in; (void)out_size; (void)ws_size;
    const float* F  = (const float*)d_in[0];  // [9216, 2048]
    const float* Wq = (const float*)d_in[1];  // [2048,2048]
    const float* bq = (const float*)d_in[2];  // [2048]
    const float* Wk = (const float*)d_in[3];  // [2048,2048]
    // d_in[4] (bk) drops out: row-constant under softmax.
    const float* Wu = (const float*)d_in[5];  // [2048,1024]
    const float* bu = (const float*)d_in[6];  // [1024]
    float* out = (float*)d_out;               // [9216, 1024]

    char* ws = (char*)d_ws;
    const long o_F16  = 0L;                      // 37748736
    const long o_Fh8  = 37748736L;
    const long o_Fl8  = 56623104L;
    const long o_Sh8  = 75497472L;
    const long o_Sl8  = 94371840L;
    const long o_adj  = 113246208L;              // 84934656
    const long o_P    = 198180864L;              // 42467328
    const long o_vT   = 240648192L;
    const long o_WuT  = 259522560L;
    const long o_Wqh  = 263716864L;
    const long o_Wql  = 267911168L;
    const long o_Wkh  = 272105472L;
    const long o_Wkl  = 276299776L;
    const long o_Mth  = 280494080L;
    const long o_Mtl  = 284688384L;
    const long o_u    = 288882688L;
    const long o_c    = 288890880L;

    u16* F16 = (u16*)(ws + o_F16);
    i8*  Fh8 = (i8*)(ws + o_Fh8);   i8* Fl8 = (i8*)(ws + o_Fl8);
    i8*  Sh8 = (i8*)(ws + o_Sh8);   i8* Sl8 = (i8*)(ws + o_Sl8);
    float* adj = (float*)(ws + o_adj);
    u16* P   = (u16*)(ws + o_P);
    u16* vT  = (u16*)(ws + o_vT);
    u16* WuT = (u16*)(ws + o_WuT);
    i8*  Wqh = (i8*)(ws + o_Wqh);   i8* Wql = (i8*)(ws + o_Wql);
    i8*  Wkh = (i8*)(ws + o_Wkh);   i8* Wkl = (i8*)(ws + o_Wkl);
    i8*  Mth = (i8*)(ws + o_Mth);   i8* Mtl = (i8*)(ws + o_Mtl);
    float* u = (float*)(ws + o_u);
    float* c = (float*)(ws + o_c);

    // --- 1: all independent pre-passes (gemv + WuT + quantW(Wq) + quantW(Wk)) ---
    prep_k<<<36864, 256, 0, stream>>>(Wk, bq, u, Wq, Wqh, Wql, Wkh, Wkl, Wu, WuT);

    // --- 2: Mt = Wk @ Wq^T (256 blocks, first) + quantFc (9216 blocks) ---
    fused_qfc_mt<<<9472, 512, 0, stream>>>(F, u, F16, Fh8, Fl8, c,
                                           Wqh, Wql, Wkh, Wkl, Mth, Mtl);

    // --- 3: S = F @ Mt^T  packed with  v = F @ Wu (vT fp16 transposed) ---
    fused_sv<<<dim3(24, 72, 1), 512, 0, stream>>>(Fh8, Fl8, Mth, Mtl, Sh8, Sl8,
                                                  F16, WuT, vT);

    // --- 4: adj = S @ F^T per batch [2304x2304]; val = comb / 5440^2 ---
    gemm_i8_k<1><<<dim3(18, 18, 4), 512, 0, stream>>>(
        Sh8, Sl8, Fh8, Fl8, nullptr, nullptr, adj,
        3.3791083e-08f, 2304, 2048,
        2304L * 2048, 2304L * 2048, 2304L * 2304);

    // --- 5: P = softmax(adj + c), fp16 ---
    softmax_k<<<dim3(2304, 4, 1), 256, 0, stream>>>(adj, c, P);

    // --- 6: out = P @ v + bu, fp32 ---
    gemm_f16_k<3><<<dim3(8, 18, 4), 512, 0, stream>>>(
        P, vT, nullptr, out, bu, 1024, 2304,
        2304L * 2304, 1024L * 2304, 2304L * 1024);
}

// Round 3
// 634.283 us; speedup vs baseline: 1.0483x; 1.0483x over previous
//
#include <hip/hip_runtime.h>

// ============================================================================
// GNN_22170621182157 R7: revert to R5 4-wave/256-thread structure (R6's
// same-block 8-wave lockstep regressed), + single-barrier K-loop:
//   old: {stage(kt+1); vmcnt(8); barrier; compute; lgkm0; barrier}
//   new: {vmcnt(0)+lgkm0; barrier; stage(kt+1); compute}
// Safe because stage is issued only after the barrier, at which point all
// waves' reads of the target buffer (step kt-1) are complete (lgkm0 enforced
// before the barrier).  One barrier per K-step, same dbuf + prefetch depth.
//
// Math (softmax row-shift invariance):
//   softmax(adj) == softmax( S F^T + 1*c^T ), S = F Mt^T, Mt = Wk Wq^T,
//   c = F (Wk bq);  out = P (F Wu) + bu.
// Fixed-point: x ~ r/s, r = a1*256 + a0 (i8 digits).  s_F=s_S=5440,
// s_W=s_Mt=261120.  comb = 65536*hh + 256*(a1b0+a0b1) + a0b0 (all i32 exact).
// ============================================================================

typedef unsigned short u16;
typedef unsigned int   u32;
typedef signed char    i8;
typedef _Float16 f16;
typedef f16    f16x8 __attribute__((ext_vector_type(8)));
typedef float  f32x4 __attribute__((ext_vector_type(4)));
typedef int    i32x4 __attribute__((ext_vector_type(4)));
typedef u32    u32x4 __attribute__((ext_vector_type(4)));
typedef u16    u16x4 __attribute__((ext_vector_type(4)));

#define WAIT_VM0_LGKM0 0x0070  // vmcnt(0), expcnt 7, lgkmcnt(0)

__device__ __forceinline__ void gload16(const void* g, void* l) {
    __builtin_amdgcn_global_load_lds(
        (const __attribute__((address_space(1))) unsigned int*)g,
        (__attribute__((address_space(3))) unsigned int*)l, 16, 0, 0);
}

__device__ __forceinline__ void tile_swizzle(int& tx, int& ty) {
    const int gx = gridDim.x, gy = gridDim.y;
    const int lin = blockIdx.y * gx + blockIdx.x;
    const int G = 4;
    const int gid = lin / (G * gx);
    const int g0 = gid * G;
    const int gh = min(G, gy - g0);
    const int rem = lin - gid * (G * gx);
    ty = g0 + rem % gh;
    tx = rem / gh;
}

__device__ __forceinline__ void digits256(float v, float s, i8& d1, i8& d0) {
    float f = fminf(fmaxf(v * s, -32600.0f), 32600.0f);
    int r = __float2int_rn(f);
    int a1 = (r + 128) >> 8;
    int a0 = r - (a1 << 8);
    d1 = (i8)a1;
    d0 = (i8)a0;
}

// ---------------------------------------------------------------------------
// i8 merged 4-term GEMM body: C = A @ Bt^T.  128x128 tile, BK=64 B, 4 waves
// 2x2, wave 4x4 of mfma_i32_16x16x64_i8; acc sets hh/cross/ll.
// Staging: global_load_lds 16B into unpadded LDS (row=64B), chunk swizzle
// slot=(kq+(row>>1))&3 -> 2-way max bank alias on ds_read_b128 (free).
// Double-buffered; SINGLE barrier per K-step: {vm0+lgkm0; barrier; stage;
// compute}.  EPI 0: requantize to digit planes.  EPI 1: fp32 out.
// Needs 2*32768 B of LDS at ldsb.  256 threads.
// ---------------------------------------------------------------------------
template <int EPI>
__device__ __forceinline__ void gemm_i8_body(
    i8* ldsb, int tx, int ty, int z,
    const i8* __restrict__ Ah, const i8* __restrict__ Al,
    const i8* __restrict__ Bh, const i8* __restrict__ Bl,
    i8* __restrict__ Qh, i8* __restrict__ Ql, float* __restrict__ Cf,
    float oscale, int N, int K, long strA, long strB, long strC) {
    // planes within one 32 KB buffer: Ah 0, Al 8K, Bh 16K, Bl 24K
    const int tid  = threadIdx.x;
    const int lane = tid & 63;
    const int wv   = tid >> 6;
    const int wm   = wv >> 1, wn = wv & 1;
    const int l16  = lane & 15, kq = lane >> 4;
    const long rowBase = (long)ty * 128;
    const long colBase = (long)tx * 128;

    const i8* pAh = Ah + (long)z * strA;
    const i8* pAl = Al + (long)z * strA;
    const i8* pBh = Bh + (long)z * strB;
    const i8* pBl = Bl + (long)z * strB;

    // ---- staging geometry (per wave: 2 row-halves per plane) ----
    const int l4r = lane >> 2, l4c = lane & 3;
    int rin[2];
    u32 voffA[2], voffB[2];
    int ldsoff[2];
    #pragma unroll
    for (int h = 0; h < 2; ++h) {
        rin[h] = h * 64 + wv * 16 + l4r;                 // row within tile
        const int kw = (l4c - (rin[h] >> 1)) & 3;        // global chunk this lane fetches
        voffA[h] = (u32)((rowBase + rin[h]) * (long)K) + kw * 16;
        voffB[h] = (u32)((colBase + rin[h]) * (long)K) + kw * 16;
        ldsoff[h] = (h * 64 + wv * 16) * 64;             // wave-uniform dest
    }

    // ---- fragment read offsets (chunk-swizzled) ----
    int aoff[4], boff[4];
    #pragma unroll
    for (int i = 0; i < 4; ++i) {
        const int rA = wm * 64 + i * 16 + l16;
        aoff[i] = rA * 64 + ((kq + (rA >> 1)) & 3) * 16;
        const int rB = wn * 64 + i * 16 + l16;
        boff[i] = rB * 64 + ((kq + (rB >> 1)) & 3) * 16;
    }

    const i32x4 izero = {0, 0, 0, 0};
    i32x4 ahh[4][4], acx[4][4], all_[4][4];
    #pragma unroll
    for (int i = 0; i < 4; ++i)
        #pragma unroll
        for (int j = 0; j < 4; ++j) { ahh[i][j] = izero; acx[i][j] = izero; all_[i][j] = izero; }

    const int nk = K >> 6;

    // issue tile 0 -> buf 0
    #pragma unroll
    for (int h = 0; h < 2; ++h) {
        gload16(pAh + voffA[h], ldsb         + ldsoff[h]);
        gload16(pAl + voffA[h], ldsb + 8192  + ldsoff[h]);
        gload16(pBh + voffB[h], ldsb + 16384 + ldsoff[h]);
        gload16(pBl + voffB[h], ldsb + 24576 + ldsoff[h]);
    }

    for (int kt = 0; kt < nk; ++kt) {
        const int cur = kt & 1;
        // tile kt landed (own DMA done) + own ds_reads of buf[1-cur] done
        __builtin_amdgcn_s_waitcnt(WAIT_VM0_LGKM0);
        __builtin_amdgcn_s_barrier();   // => all waves done with buf[1-cur]

        if (kt + 1 < nk) {              // stage kt+1 into buf[1-cur]: safe now
            const long ko = (long)(kt + 1) * 64;
            i8* nb = ldsb + (1 - cur) * 32768;
            #pragma unroll
            for (int h = 0; h < 2; ++h) {
                gload16(pAh + voffA[h] + ko, nb         + ldsoff[h]);
                gload16(pAl + voffA[h] + ko, nb + 8192  + ldsoff[h]);
                gload16(pBh + voffB[h] + ko, nb + 16384 + ldsoff[h]);
                gload16(pBl + voffB[h] + ko, nb + 24576 + ldsoff[h]);
            }
        }

        const i8* base = ldsb + cur * 32768;
        i32x4 fbh[4], fbl[4];
        #pragma unroll
        for (int j = 0; j < 4; ++j) {
            fbh[j] = *(const i32x4*)(base + 16384 + boff[j]);
            fbl[j] = *(const i32x4*)(base + 24576 + boff[j]);
        }
        #pragma unroll
        for (int i = 0; i < 4; ++i) {
            i32x4 fah = *(const i32x4*)(base + aoff[i]);
            i32x4 fal = *(const i32x4*)(base + 8192 + aoff[i]);
            #pragma unroll
            for (int j = 0; j < 4; ++j) {
                ahh[i][j]  = __builtin_amdgcn_mfma_i32_16x16x64_i8(fah, fbh[j], ahh[i][j], 0, 0, 0);
                acx[i][j]  = __builtin_amdgcn_mfma_i32_16x16x64_i8(fah, fbl[j], acx[i][j], 0, 0, 0);
                acx[i][j]  = __builtin_amdgcn_mfma_i32_16x16x64_i8(fal, fbh[j], acx[i][j], 0, 0, 0);
                all_[i][j] = __builtin_amdgcn_mfma_i32_16x16x64_i8(fal, fbl[j], all_[i][j], 0, 0, 0);
            }
        }
    }

    // epilogue: C/D layout col=lane&15, row=(lane>>4)*4+reg
    #pragma unroll
    for (int i = 0; i < 4; ++i) {
        const long gr0 = rowBase + wm * 64 + i * 16 + kq * 4;
        #pragma unroll
        for (int j = 0; j < 4; ++j) {
            const long gc = colBase + wn * 64 + j * 16 + l16;
            #pragma unroll
            for (int r = 0; r < 4; ++r) {
                const float comb = 65536.0f * (float)ahh[i][j][r] +
                                     256.0f * (float)acx[i][j][r] +
                                             (float)all_[i][j][r];
                const long o = (gr0 + r) * (long)N + gc;
                if constexpr (EPI == 0) {
                    i8 d1, d0;
                    digits256(comb, oscale, d1, d0);
                    Qh[o] = d1;
                    Ql[o] = d0;
                } else {
                    Cf[(long)z * strC + o] = comb * oscale;
                }
            }
        }
    }
}

// ---------------------------------------------------------------------------
// fp16 GEMM body: C = A @ Bt^T, BK=32 (64 B rows - same staging geometry),
// 4 waves 2x2, wave 4x4 frags.  Single-barrier K-loop as in i8 body.
// EPI 2: fp16 transposed write (vT);  EPI 3: fp32 + bias[col].
// Needs 2*16384 B of LDS at ldsb.  256 threads.
// ---------------------------------------------------------------------------
template <int EPI>
__device__ __forceinline__ void gemm_f16_body(
    i8* ldsb, int tx, int ty, int z,
    const u16* __restrict__ A, const u16* __restrict__ B,
    u16* __restrict__ Ch, float* __restrict__ Cf,
    const float* __restrict__ bias,
    int N, int K, long strA, long strB, long strC) {
    // planes within one 16 KB buffer: A 0, B 8K
    const int tid  = threadIdx.x;
    const int lane = tid & 63;
    const int wv   = tid >> 6;
    const int wm   = wv >> 1, wn = wv & 1;
    const int l16  = lane & 15, kq = lane >> 4;
    const long rowBase = (long)ty * 128;
    const long colBase = (long)tx * 128;

    const u16* pA = A + (long)z * strA;
    const u16* pB = B + (long)z * strB;

    const int l4r = lane >> 2, l4c = lane & 3;
    u32 voffA[2], voffB[2];   // element (u16) units
    int ldsoff[2];            // byte units
    #pragma unroll
    for (int h = 0; h < 2; ++h) {
        const int rin = h * 64 + wv * 16 + l4r;
        const int kw = (l4c - (rin >> 1)) & 3;
        voffA[h] = (u32)((rowBase + rin) * (long)K) + kw * 8;
        voffB[h] = (u32)((colBase + rin) * (long)K) + kw * 8;
        ldsoff[h] = (h * 64 + wv * 16) * 64;
    }
    int aoff[4], boff[4];
    #pragma unroll
    for (int i = 0; i < 4; ++i) {
        const int rA = wm * 64 + i * 16 + l16;
        aoff[i] = rA * 64 + ((kq + (rA >> 1)) & 3) * 16;
        const int rB = wn * 64 + i * 16 + l16;
        boff[i] = rB * 64 + ((kq + (rB >> 1)) & 3) * 16;
    }

    const f32x4 vzero = {0.f, 0.f, 0.f, 0.f};
    f32x4 acc[4][4];
    #pragma unroll
    for (int i = 0; i < 4; ++i)
        #pragma unroll
        for (int j = 0; j < 4; ++j) acc[i][j] = vzero;

    const int nk = K >> 5;

    #pragma unroll
    for (int h = 0; h < 2; ++h) {
        gload16(pA + voffA[h], ldsb        + ldsoff[h]);
        gload16(pB + voffB[h], ldsb + 8192 + ldsoff[h]);
    }

    for (int kt = 0; kt < nk; ++kt) {
        const int cur = kt & 1;
        __builtin_amdgcn_s_waitcnt(WAIT_VM0_LGKM0);
        __builtin_amdgcn_s_barrier();

        if (kt + 1 < nk) {
            const long ko = (long)(kt + 1) * 32;
            i8* nb = ldsb + (1 - cur) * 16384;
            #pragma unroll
            for (int h = 0; h < 2; ++h) {
                gload16(pA + voffA[h] + ko, nb        + ldsoff[h]);
                gload16(pB + voffB[h] + ko, nb + 8192 + ldsoff[h]);
            }
        }

        const i8* base = ldsb + cur * 16384;
        f16x8 fa[4];
        #pragma unroll
        for (int i = 0; i < 4; ++i)
            fa[i] = __builtin_bit_cast(f16x8, *(const u32x4*)(base + aoff[i]));
        #pragma unroll
        for (int j = 0; j < 4; ++j) {
            f16x8 fb = __builtin_bit_cast(f16x8, *(const u32x4*)(base + 8192 + boff[j]));
            #pragma unroll
            for (int i = 0; i < 4; ++i)
                acc[i][j] = __builtin_amdgcn_mfma_f32_16x16x32_f16(fa[i], fb, acc[i][j], 0, 0, 0);
        }
    }

    #pragma unroll
    for (int i = 0; i < 4; ++i) {
        const long gr0 = rowBase + wm * 64 + i * 16 + kq * 4;
        #pragma unroll
        for (int j = 0; j < 4; ++j) {
            const long gc = colBase + wn * 64 + j * 16 + l16;
            f32x4 a = acc[i][j];
            if constexpr (EPI == 2) {
                const int b  = (int)(gr0 / 2304);
                const int n0 = (int)(gr0 - (long)b * 2304);
                u16x4 o4;
                #pragma unroll
                for (int r = 0; r < 4; ++r) o4[r] = __builtin_bit_cast(u16, (f16)a[r]);
                *(u16x4*)&Ch[(long)b * (1024L * 2304) + gc * 2304 + n0] = o4;
            } else {
                float* C = Cf + (long)z * strC;
                const float bv = bias[gc];
                #pragma unroll
                for (int r = 0; r < 4; ++r) C[(gr0 + r) * (long)N + gc] = a[r] + bv;
            }
        }
    }
}

// ---------------------------------------------------------------------------
// quantFc body (256 threads): F fp32 -> fp16 + i8 digit planes (scale 5440)
// + c[row] = F[row].u.  red must point to >=4 floats of shared memory.
// ---------------------------------------------------------------------------
__device__ __forceinline__ void quantFc_body(long row, float* red,
                                             const float* __restrict__ F,
                                             const float* __restrict__ u,
                                             u16* __restrict__ F16,
                                             i8* __restrict__ hi,
                                             i8* __restrict__ lo,
                                             float* __restrict__ c) {
    const int tid = threadIdx.x;
    const float* fr = F + row * 2048;
    float dot = 0.f;
    #pragma unroll
    for (int t = 0; t < 8; ++t) {
        const int i = t * 256 + tid;
        const float v = fr[i];
        F16[row * 2048 + i] = __builtin_bit_cast(u16, (f16)v);
        i8 d1, d0;
        digits256(v, 5440.0f, d1, d0);
        hi[row * 2048 + i] = d1;
        lo[row * 2048 + i] = d0;
        dot += v * u[i];
    }
    #pragma unroll
    for (int off = 32; off >= 1; off >>= 1) dot += __shfl_down(dot, off);
    if ((tid & 63) == 0) red[tid >> 6] = dot;
    __syncthreads();
    if (tid == 0) c[row] = red[0] + red[1] + red[2] + red[3];
}

// ---------------------------------------------------------------------------
// prep_k: all independent pre-passes in one launch (256 threads).
//   blocks [0,2048)      : u[row] = Wk[row,:] . bq
//   blocks [2048,4096)   : WuT transpose tile (32x32)
//   blocks [4096,20480)  : quantW(Wq)
//   blocks [20480,36864) : quantW(Wk)
// ---------------------------------------------------------------------------
__global__ __launch_bounds__(256) void prep_k(const float* __restrict__ Wk,
                                              const float* __restrict__ bq,
                                              float* __restrict__ u,
                                              const float* __restrict__ Wq,
                                              i8* __restrict__ Wqh, i8* __restrict__ Wql,
                                              i8* __restrict__ Wkh, i8* __restrict__ Wkl,
                                              const float* __restrict__ Wu,
                                              u16* __restrict__ WuT) {
    __shared__ __align__(16) float sm[32 * 33];
    const int tid = threadIdx.x;
    const int id = blockIdx.x;
    if (id < 2048) {
        // gemv: u[id] = Wk[id,:] . bq
        const float* ar = Wk + (long)id * 2048;
        float s = 0.f;
        #pragma unroll
        for (int t = 0; t < 8; ++t) s += ar[t * 256 + tid] * bq[t * 256 + tid];
        #pragma unroll
        for (int off = 32; off >= 1; off >>= 1) s += __shfl_down(s, off);
        if ((tid & 63) == 0) sm[tid >> 6] = s;
        __syncthreads();
        if (tid == 0) u[id] = sm[0] + sm[1] + sm[2] + sm[3];
    } else if (id < 4096) {
        // WuT: Wu [2048][1024] -> WuT [1024][2048] fp16
        const int w  = id - 2048;
        const int bx = (w & 31) * 32;   // col tile of Wu
        const int by = (w >> 5) * 32;   // row tile of Wu
        const int lx = tid & 31, ly = tid >> 5;
        float (*t)[33] = (float (*)[33])sm;
        #pragma unroll
        for (int dy = 0; dy < 32; dy += 8)
            t[ly + dy][lx] = Wu[(long)(by + ly + dy) * 1024 + bx + lx];
        __syncthreads();
        #pragma unroll
        for (int dy = 0; dy < 32; dy += 8)
            WuT[(long)(bx + ly + dy) * 2048 + by + lx] =
                __builtin_bit_cast(u16, (f16)t[lx][ly + dy]);
    } else {
        long j = (long)id - 4096;       // 0..32767 block-units of 256 elems
        const float* src;
        i8 *dh, *dl;
        if (j < 16384) { src = Wq; dh = Wqh; dl = Wql; }
        else           { j -= 16384; src = Wk; dh = Wkh; dl = Wkl; }
        const long i = j * 256 + tid;   // < 4194304
        i8 d1, d0;
        digits256(src[i], 261120.0f, d1, d0);
        dh[i] = d1;
        dl[i] = d0;
    }
}

// ---------------------------------------------------------------------------
// fused_qfc_mt (256 threads): Mt = Wk @ Wq^T (blocks 0..255, launched first -
// on the critical path to S) packed with quantFc (blocks 256..9471, BW-bound).
// ---------------------------------------------------------------------------
__global__ __launch_bounds__(256, 2) void fused_qfc_mt(
    const float* __restrict__ F, const float* __restrict__ u,
    u16* __restrict__ F16, i8* __restrict__ Fh, i8* __restrict__ Fl,
    float* __restrict__ c,
    const i8* __restrict__ Wqh, const i8* __restrict__ Wql,
    const i8* __restrict__ Wkh, const i8* __restrict__ Wkl,
    i8* __restrict__ Mth, i8* __restrict__ Mtl) {
    __shared__ __align__(16) i8 lds[2][32768];
    const int b = blockIdx.x;
    if (b < 256) {
        gemm_i8_body<0>(&lds[0][0], b & 15, b >> 4, 0,
                        Wkh, Wkl, Wqh, Wql, Mth, Mtl, nullptr,
                        3.8296569e-06f, 2048, 2048, 0L, 0L, 0L);
    } else {
        quantFc_body((long)b - 256, (float*)&lds[0][0], F, u, F16, Fh, Fl, c);
    }
}

// ---------------------------------------------------------------------------
// fused_sv (256 threads): S = F @ Mt^T (bx<16) packed with v = F16 @ WuT^T
// -> vT (bx>=16).  Grid (24, 72): v blocks fill S's scheduling tail.
// ---------------------------------------------------------------------------
__global__ __launch_bounds__(256, 2) void fused_sv(
    const i8* __restrict__ Fh, const i8* __restrict__ Fl,
    const i8* __restrict__ Mth, const i8* __restrict__ Mtl,
    i8* __restrict__ Sh, i8* __restrict__ Sl,
    const u16* __restrict__ F16, const u16* __restrict__ WuT,
    u16* __restrict__ vT) {
    __shared__ __align__(16) i8 lds[2][32768];
    const int bx = blockIdx.x, by = blockIdx.y;
    if (bx < 16) {
        gemm_i8_body<0>(&lds[0][0], bx, by, 0,
                        Fh, Fl, Mth, Mtl, Sh, Sl, nullptr,
                        3.8296569e-06f, 2048, 2048, 0L, 0L, 0L);
    } else {
        gemm_f16_body<2>(&lds[0][0], bx - 16, by, 0,
                         F16, WuT, vT, nullptr, nullptr,
                         1024, 2048, 0L, 0L, 0L);
    }
}

// ---------------------------------------------------------------------------
// Standalone GEMM wrappers (adj and out; keep XCD/L2 tile swizzle).
// ---------------------------------------------------------------------------
template <int EPI>
__global__ __launch_bounds__(256, 2) void gemm_i8_k(
    const i8* __restrict__ Ah, const i8* __restrict__ Al,
    const i8* __restrict__ Bh, const i8* __restrict__ Bl,
    i8* __restrict__ Qh, i8* __restrict__ Ql, float* __restrict__ Cf,
    float oscale, int N, int K, long strA, long strB, long strC) {
    __shared__ __align__(16) i8 lds[2][32768];
    int tx, ty;
    tile_swizzle(tx, ty);
    gemm_i8_body<EPI>(&lds[0][0], tx, ty, blockIdx.z,
                      Ah, Al, Bh, Bl, Qh, Ql, Cf, oscale, N, K, strA, strB, strC);
}

template <int EPI>
__global__ __launch_bounds__(256, 3) void gemm_f16_k(
    const u16* __restrict__ A, const u16* __restrict__ B,
    u16* __restrict__ Ch, float* __restrict__ Cf,
    const float* __restrict__ bias,
    int N, int K, long strA, long strB, long strC) {
    __shared__ __align__(16) i8 lds[2][16384];
    int tx, ty;
    tile_swizzle(tx, ty);
    gemm_f16_body<EPI>(&lds[0][0], tx, ty, blockIdx.z,
                       A, B, Ch, Cf, bias, N, K, strA, strB, strC);
}

// ---------------------------------------------------------------------------
// Row softmax over 2304 cols with per-column bias c[m]; fp32 in, fp16 out.
// ---------------------------------------------------------------------------
__global__ __launch_bounds__(256) void softmax_k(const float* __restrict__ adj,
                                                 const float* __restrict__ c,
                                                 u16* __restrict__ P) {
    const int n = 2304;
    const int row = blockIdx.x, b = blockIdx.y;
    const int tid = threadIdx.x;
    const float* ar = adj + ((long)b * n + row) * (long)n;
    const float* cb = c + (long)b * n;
    u16* pr = P + ((long)b * n + row) * (long)n;

    float v[9];
    float mx = -3.0e38f;
    #pragma unroll
    for (int t = 0; t < 9; ++t) {
        const int i = t * 256 + tid;
        const float x = ar[i] + cb[i];
        v[t] = x;
        mx = fmaxf(mx, x);
    }
    #pragma unroll
    for (int off = 32; off >= 1; off >>= 1) mx = fmaxf(mx, __shfl_down(mx, off));
    __shared__ float red[4];
    if ((tid & 63) == 0) red[tid >> 6] = mx;
    __syncthreads();
    mx = fmaxf(fmaxf(red[0], red[1]), fmaxf(red[2], red[3]));

    float s = 0.f;
    #pragma unroll
    for (int t = 0; t < 9; ++t) {
        const float e = __expf(v[t] - mx);
        v[t] = e;
        s += e;
    }
    #pragma unroll
    for (int off = 32; off >= 1; off >>= 1) s += __shfl_down(s, off);
    __shared__ float red2[4];
    if ((tid & 63) == 0) red2[tid >> 6] = s;
    __syncthreads();
    s = red2[0] + red2[1] + red2[2] + red2[3];
    const float inv = 1.0f / s;
    #pragma unroll
    for (int t = 0; t < 9; ++t)
        pr[t * 256 + tid] = __builtin_bit_cast(u16, (f16)(v[t] * inv));
}

// ---------------------------------------------------------------------------
// Host launch
// ---------------------------------------------------------------------------
extern "C" void kernel_launch(void* const* d_in, const int* in_sizes, int n_in,
                              void* d_out, int out_size, void* d_ws, size_t ws_size,
                              hipStream_t stream) {
    (void)in_sizes; (void)n_in; (void)out_size; (void)ws_size;
    const float* F  = (const float*)d_in[0];  // [9216, 2048]
    const float* Wq = (const float*)d_in[1];  // [2048,2048]
    const float* bq = (const float*)d_in[2];  // [2048]
    const float* Wk = (const float*)d_in[3];  // [2048,2048]
    // d_in[4] (bk) drops out: row-constant under softmax.
    const float* Wu = (const float*)d_in[5];  // [2048,1024]
    const float* bu = (const float*)d_in[6];  // [1024]
    float* out = (float*)d_out;               // [9216, 1024]

    char* ws = (char*)d_ws;
    const long o_F16  = 0L;                      // 37748736
    const long o_Fh8  = 37748736L;
    const long o_Fl8  = 56623104L;
    const long o_Sh8  = 75497472L;
    const long o_Sl8  = 94371840L;
    const long o_adj  = 113246208L;              // 84934656
    const long o_P    = 198180864L;              // 42467328
    const long o_vT   = 240648192L;
    const long o_WuT  = 259522560L;
    const long o_Wqh  = 263716864L;
    const long o_Wql  = 267911168L;
    const long o_Wkh  = 272105472L;
    const long o_Wkl  = 276299776L;
    const long o_Mth  = 280494080L;
    const long o_Mtl  = 284688384L;
    const long o_u    = 288882688L;
    const long o_c    = 288890880L;

    u16* F16 = (u16*)(ws + o_F16);
    i8*  Fh8 = (i8*)(ws + o_Fh8);   i8* Fl8 = (i8*)(ws + o_Fl8);
    i8*  Sh8 = (i8*)(ws + o_Sh8);   i8* Sl8 = (i8*)(ws + o_Sl8);
    float* adj = (float*)(ws + o_adj);
    u16* P   = (u16*)(ws + o_P);
    u16* vT  = (u16*)(ws + o_vT);
    u16* WuT = (u16*)(ws + o_WuT);
    i8*  Wqh = (i8*)(ws + o_Wqh);   i8* Wql = (i8*)(ws + o_Wql);
    i8*  Wkh = (i8*)(ws + o_Wkh);   i8* Wkl = (i8*)(ws + o_Wkl);
    i8*  Mth = (i8*)(ws + o_Mth);   i8* Mtl = (i8*)(ws + o_Mtl);
    float* u = (float*)(ws + o_u);
    float* c = (float*)(ws + o_c);

    // --- 1: all independent pre-passes (gemv + WuT + quantW(Wq) + quantW(Wk)) ---
    prep_k<<<36864, 256, 0, stream>>>(Wk, bq, u, Wq, Wqh, Wql, Wkh, Wkl, Wu, WuT);

    // --- 2: Mt = Wk @ Wq^T (256 blocks, first) + quantFc (9216 blocks) ---
    fused_qfc_mt<<<9472, 256, 0, stream>>>(F, u, F16, Fh8, Fl8, c,
                                           Wqh, Wql, Wkh, Wkl, Mth, Mtl);

    // --- 3: S = F @ Mt^T  packed with  v = F @ Wu (vT fp16 transposed) ---
    fused_sv<<<dim3(24, 72, 1), 256, 0, stream>>>(Fh8, Fl8, Mth, Mtl, Sh8, Sl8,
                                                  F16, WuT, vT);

    // --- 4: adj = S @ F^T per batch [2304x2304]; val = comb / 5440^2 ---
    gemm_i8_k<1><<<dim3(18, 18, 4), 256, 0, stream>>>(
        Sh8, Sl8, Fh8, Fl8, nullptr, nullptr, adj,
        3.3791083e-08f, 2304, 2048,
        2304L * 2048, 2304L * 2048, 2304L * 2304);

    // --- 5: P = softmax(adj + c), fp16 ---
    softmax_k<<<dim3(2304, 4, 1), 256, 0, stream>>>(adj, c, P);

    // --- 6: out = P @ v + bu, fp32 ---
    gemm_f16_k<3><<<dim3(8, 18, 4), 256, 0, stream>>>(
        P, vT, nullptr, out, bu, 1024, 2304,
        2304L * 2304, 1024L * 2304, 2304L * 1024);
}

// Round 4
// 623.966 us; speedup vs baseline: 1.0656x; 1.0165x over previous
//
#include <hip/hip_runtime.h>

// ============================================================================
// GNN_22170621182157 R8: R7 base (4-wave/256-thr, single-barrier K-loop)
//   + T5 s_setprio(1) around the ds_read+MFMA cluster (prio 0 during
//     stage/wait/barrier) - favors the MFMA-phase block of the 2 blocks/CU.
//   + acx RAW de-serialization: per-i passes {ahh x4, acx_a x4, all x4,
//     acx_b x4} so dependent acx pairs are 4-7 MFMAs apart.
//
// Math (softmax row-shift invariance):
//   softmax(adj) == softmax( S F^T + 1*c^T ), S = F Mt^T, Mt = Wk Wq^T,
//   c = F (Wk bq);  out = P (F Wu) + bu.
// Fixed-point: x ~ r/s, r = a1*256 + a0 (i8 digits).  s_F=s_S=5440,
// s_W=s_Mt=261120.  comb = 65536*hh + 256*(a1b0+a0b1) + a0b0 (all i32 exact).
// ============================================================================

typedef unsigned short u16;
typedef unsigned int   u32;
typedef signed char    i8;
typedef _Float16 f16;
typedef f16    f16x8 __attribute__((ext_vector_type(8)));
typedef float  f32x4 __attribute__((ext_vector_type(4)));
typedef int    i32x4 __attribute__((ext_vector_type(4)));
typedef u32    u32x4 __attribute__((ext_vector_type(4)));
typedef u16    u16x4 __attribute__((ext_vector_type(4)));

#define WAIT_VM0_LGKM0 0x0070  // vmcnt(0), expcnt 7, lgkmcnt(0)

__device__ __forceinline__ void gload16(const void* g, void* l) {
    __builtin_amdgcn_global_load_lds(
        (const __attribute__((address_space(1))) unsigned int*)g,
        (__attribute__((address_space(3))) unsigned int*)l, 16, 0, 0);
}

__device__ __forceinline__ void tile_swizzle(int& tx, int& ty) {
    const int gx = gridDim.x, gy = gridDim.y;
    const int lin = blockIdx.y * gx + blockIdx.x;
    const int G = 4;
    const int gid = lin / (G * gx);
    const int g0 = gid * G;
    const int gh = min(G, gy - g0);
    const int rem = lin - gid * (G * gx);
    ty = g0 + rem % gh;
    tx = rem / gh;
}

__device__ __forceinline__ void digits256(float v, float s, i8& d1, i8& d0) {
    float f = fminf(fmaxf(v * s, -32600.0f), 32600.0f);
    int r = __float2int_rn(f);
    int a1 = (r + 128) >> 8;
    int a0 = r - (a1 << 8);
    d1 = (i8)a1;
    d0 = (i8)a0;
}

// ---------------------------------------------------------------------------
// i8 merged 4-term GEMM body: C = A @ Bt^T.  128x128 tile, BK=64 B, 4 waves
// 2x2, wave 4x4 of mfma_i32_16x16x64_i8; acc sets hh/cross/ll.
// Staging: global_load_lds 16B into unpadded LDS (row=64B), chunk swizzle
// slot=(kq+(row>>1))&3 -> 2-way max bank alias on ds_read_b128 (free).
// Double-buffered; single barrier per K-step: {vm0+lgkm0; barrier; stage;
// setprio(1); compute; setprio(0)}.
// EPI 0: requantize to digit planes.  EPI 1: fp32 out.
// Needs 2*32768 B of LDS at ldsb.  256 threads.
// ---------------------------------------------------------------------------
template <int EPI>
__device__ __forceinline__ void gemm_i8_body(
    i8* ldsb, int tx, int ty, int z,
    const i8* __restrict__ Ah, const i8* __restrict__ Al,
    const i8* __restrict__ Bh, const i8* __restrict__ Bl,
    i8* __restrict__ Qh, i8* __restrict__ Ql, float* __restrict__ Cf,
    float oscale, int N, int K, long strA, long strB, long strC) {
    // planes within one 32 KB buffer: Ah 0, Al 8K, Bh 16K, Bl 24K
    const int tid  = threadIdx.x;
    const int lane = tid & 63;
    const int wv   = tid >> 6;
    const int wm   = wv >> 1, wn = wv & 1;
    const int l16  = lane & 15, kq = lane >> 4;
    const long rowBase = (long)ty * 128;
    const long colBase = (long)tx * 128;

    const i8* pAh = Ah + (long)z * strA;
    const i8* pAl = Al + (long)z * strA;
    const i8* pBh = Bh + (long)z * strB;
    const i8* pBl = Bl + (long)z * strB;

    // ---- staging geometry (per wave: 2 row-halves per plane) ----
    const int l4r = lane >> 2, l4c = lane & 3;
    int rin[2];
    u32 voffA[2], voffB[2];
    int ldsoff[2];
    #pragma unroll
    for (int h = 0; h < 2; ++h) {
        rin[h] = h * 64 + wv * 16 + l4r;                 // row within tile
        const int kw = (l4c - (rin[h] >> 1)) & 3;        // global chunk this lane fetches
        voffA[h] = (u32)((rowBase + rin[h]) * (long)K) + kw * 16;
        voffB[h] = (u32)((colBase + rin[h]) * (long)K) + kw * 16;
        ldsoff[h] = (h * 64 + wv * 16) * 64;             // wave-uniform dest
    }

    // ---- fragment read offsets (chunk-swizzled) ----
    int aoff[4], boff[4];
    #pragma unroll
    for (int i = 0; i < 4; ++i) {
        const int rA = wm * 64 + i * 16 + l16;
        aoff[i] = rA * 64 + ((kq + (rA >> 1)) & 3) * 16;
        const int rB = wn * 64 + i * 16 + l16;
        boff[i] = rB * 64 + ((kq + (rB >> 1)) & 3) * 16;
    }

    const i32x4 izero = {0, 0, 0, 0};
    i32x4 ahh[4][4], acx[4][4], all_[4][4];
    #pragma unroll
    for (int i = 0; i < 4; ++i)
        #pragma unroll
        for (int j = 0; j < 4; ++j) { ahh[i][j] = izero; acx[i][j] = izero; all_[i][j] = izero; }

    const int nk = K >> 6;

    // issue tile 0 -> buf 0
    #pragma unroll
    for (int h = 0; h < 2; ++h) {
        gload16(pAh + voffA[h], ldsb         + ldsoff[h]);
        gload16(pAl + voffA[h], ldsb + 8192  + ldsoff[h]);
        gload16(pBh + voffB[h], ldsb + 16384 + ldsoff[h]);
        gload16(pBl + voffB[h], ldsb + 24576 + ldsoff[h]);
    }

    for (int kt = 0; kt < nk; ++kt) {
        const int cur = kt & 1;
        // tile kt landed (own DMA done) + own ds_reads of buf[1-cur] done
        __builtin_amdgcn_s_waitcnt(WAIT_VM0_LGKM0);
        __builtin_amdgcn_s_barrier();   // => all waves done with buf[1-cur]

        if (kt + 1 < nk) {              // stage kt+1 into buf[1-cur]: safe now
            const long ko = (long)(kt + 1) * 64;
            i8* nb = ldsb + (1 - cur) * 32768;
            #pragma unroll
            for (int h = 0; h < 2; ++h) {
                gload16(pAh + voffA[h] + ko, nb         + ldsoff[h]);
                gload16(pAl + voffA[h] + ko, nb + 8192  + ldsoff[h]);
                gload16(pBh + voffB[h] + ko, nb + 16384 + ldsoff[h]);
                gload16(pBl + voffB[h] + ko, nb + 24576 + ldsoff[h]);
            }
        }

        __builtin_amdgcn_s_setprio(1);  // MFMA-phase wave wins CU arbitration
        const i8* base = ldsb + cur * 32768;
        i32x4 fbh[4], fbl[4];
        #pragma unroll
        for (int j = 0; j < 4; ++j) {
            fbh[j] = *(const i32x4*)(base + 16384 + boff[j]);
            fbl[j] = *(const i32x4*)(base + 24576 + boff[j]);
        }
        #pragma unroll
        for (int i = 0; i < 4; ++i) {
            i32x4 fah = *(const i32x4*)(base + aoff[i]);
            i32x4 fal = *(const i32x4*)(base + 8192 + aoff[i]);
            // de-serialized: dependent acx pairs separated by 4-7 MFMAs
            #pragma unroll
            for (int j = 0; j < 4; ++j)
                ahh[i][j]  = __builtin_amdgcn_mfma_i32_16x16x64_i8(fah, fbh[j], ahh[i][j], 0, 0, 0);
            #pragma unroll
            for (int j = 0; j < 4; ++j)
                acx[i][j]  = __builtin_amdgcn_mfma_i32_16x16x64_i8(fah, fbl[j], acx[i][j], 0, 0, 0);
            #pragma unroll
            for (int j = 0; j < 4; ++j)
                all_[i][j] = __builtin_amdgcn_mfma_i32_16x16x64_i8(fal, fbl[j], all_[i][j], 0, 0, 0);
            #pragma unroll
            for (int j = 0; j < 4; ++j)
                acx[i][j]  = __builtin_amdgcn_mfma_i32_16x16x64_i8(fal, fbh[j], acx[i][j], 0, 0, 0);
        }
        __builtin_amdgcn_s_setprio(0);
    }

    // epilogue: C/D layout col=lane&15, row=(lane>>4)*4+reg
    #pragma unroll
    for (int i = 0; i < 4; ++i) {
        const long gr0 = rowBase + wm * 64 + i * 16 + kq * 4;
        #pragma unroll
        for (int j = 0; j < 4; ++j) {
            const long gc = colBase + wn * 64 + j * 16 + l16;
            #pragma unroll
            for (int r = 0; r < 4; ++r) {
                const float comb = 65536.0f * (float)ahh[i][j][r] +
                                     256.0f * (float)acx[i][j][r] +
                                             (float)all_[i][j][r];
                const long o = (gr0 + r) * (long)N + gc;
                if constexpr (EPI == 0) {
                    i8 d1, d0;
                    digits256(comb, oscale, d1, d0);
                    Qh[o] = d1;
                    Ql[o] = d0;
                } else {
                    Cf[(long)z * strC + o] = comb * oscale;
                }
            }
        }
    }
}

// ---------------------------------------------------------------------------
// fp16 GEMM body: C = A @ Bt^T, BK=32 (64 B rows - same staging geometry),
// 4 waves 2x2, wave 4x4 frags.  Single-barrier K-loop + setprio as i8 body.
// EPI 2: fp16 transposed write (vT);  EPI 3: fp32 + bias[col].
// Needs 2*16384 B of LDS at ldsb.  256 threads.
// ---------------------------------------------------------------------------
template <int EPI>
__device__ __forceinline__ void gemm_f16_body(
    i8* ldsb, int tx, int ty, int z,
    const u16* __restrict__ A, const u16* __restrict__ B,
    u16* __restrict__ Ch, float* __restrict__ Cf,
    const float* __restrict__ bias,
    int N, int K, long strA, long strB, long strC) {
    // planes within one 16 KB buffer: A 0, B 8K
    const int tid  = threadIdx.x;
    const int lane = tid & 63;
    const int wv   = tid >> 6;
    const int wm   = wv >> 1, wn = wv & 1;
    const int l16  = lane & 15, kq = lane >> 4;
    const long rowBase = (long)ty * 128;
    const long colBase = (long)tx * 128;

    const u16* pA = A + (long)z * strA;
    const u16* pB = B + (long)z * strB;

    const int l4r = lane >> 2, l4c = lane & 3;
    u32 voffA[2], voffB[2];   // element (u16) units
    int ldsoff[2];            // byte units
    #pragma unroll
    for (int h = 0; h < 2; ++h) {
        const int rin = h * 64 + wv * 16 + l4r;
        const int kw = (l4c - (rin >> 1)) & 3;
        voffA[h] = (u32)((rowBase + rin) * (long)K) + kw * 8;
        voffB[h] = (u32)((colBase + rin) * (long)K) + kw * 8;
        ldsoff[h] = (h * 64 + wv * 16) * 64;
    }
    int aoff[4], boff[4];
    #pragma unroll
    for (int i = 0; i < 4; ++i) {
        const int rA = wm * 64 + i * 16 + l16;
        aoff[i] = rA * 64 + ((kq + (rA >> 1)) & 3) * 16;
        const int rB = wn * 64 + i * 16 + l16;
        boff[i] = rB * 64 + ((kq + (rB >> 1)) & 3) * 16;
    }

    const f32x4 vzero = {0.f, 0.f, 0.f, 0.f};
    f32x4 acc[4][4];
    #pragma unroll
    for (int i = 0; i < 4; ++i)
        #pragma unroll
        for (int j = 0; j < 4; ++j) acc[i][j] = vzero;

    const int nk = K >> 5;

    #pragma unroll
    for (int h = 0; h < 2; ++h) {
        gload16(pA + voffA[h], ldsb        + ldsoff[h]);
        gload16(pB + voffB[h], ldsb + 8192 + ldsoff[h]);
    }

    for (int kt = 0; kt < nk; ++kt) {
        const int cur = kt & 1;
        __builtin_amdgcn_s_waitcnt(WAIT_VM0_LGKM0);
        __builtin_amdgcn_s_barrier();

        if (kt + 1 < nk) {
            const long ko = (long)(kt + 1) * 32;
            i8* nb = ldsb + (1 - cur) * 16384;
            #pragma unroll
            for (int h = 0; h < 2; ++h) {
                gload16(pA + voffA[h] + ko, nb        + ldsoff[h]);
                gload16(pB + voffB[h] + ko, nb + 8192 + ldsoff[h]);
            }
        }

        __builtin_amdgcn_s_setprio(1);
        const i8* base = ldsb + cur * 16384;
        f16x8 fa[4];
        #pragma unroll
        for (int i = 0; i < 4; ++i)
            fa[i] = __builtin_bit_cast(f16x8, *(const u32x4*)(base + aoff[i]));
        #pragma unroll
        for (int j = 0; j < 4; ++j) {
            f16x8 fb = __builtin_bit_cast(f16x8, *(const u32x4*)(base + 8192 + boff[j]));
            #pragma unroll
            for (int i = 0; i < 4; ++i)
                acc[i][j] = __builtin_amdgcn_mfma_f32_16x16x32_f16(fa[i], fb, acc[i][j], 0, 0, 0);
        }
        __builtin_amdgcn_s_setprio(0);
    }

    #pragma unroll
    for (int i = 0; i < 4; ++i) {
        const long gr0 = rowBase + wm * 64 + i * 16 + kq * 4;
        #pragma unroll
        for (int j = 0; j < 4; ++j) {
            const long gc = colBase + wn * 64 + j * 16 + l16;
            f32x4 a = acc[i][j];
            if constexpr (EPI == 2) {
                const int b  = (int)(gr0 / 2304);
                const int n0 = (int)(gr0 - (long)b * 2304);
                u16x4 o4;
                #pragma unroll
                for (int r = 0; r < 4; ++r) o4[r] = __builtin_bit_cast(u16, (f16)a[r]);
                *(u16x4*)&Ch[(long)b * (1024L * 2304) + gc * 2304 + n0] = o4;
            } else {
                float* C = Cf + (long)z * strC;
                const float bv = bias[gc];
                #pragma unroll
                for (int r = 0; r < 4; ++r) C[(gr0 + r) * (long)N + gc] = a[r] + bv;
            }
        }
    }
}

// ---------------------------------------------------------------------------
// quantFc body (256 threads): F fp32 -> fp16 + i8 digit planes (scale 5440)
// + c[row] = F[row].u.  red must point to >=4 floats of shared memory.
// ---------------------------------------------------------------------------
__device__ __forceinline__ void quantFc_body(long row, float* red,
                                             const float* __restrict__ F,
                                             const float* __restrict__ u,
                                             u16* __restrict__ F16,
                                             i8* __restrict__ hi,
                                             i8* __restrict__ lo,
                                             float* __restrict__ c) {
    const int tid = threadIdx.x;
    const float* fr = F + row * 2048;
    float dot = 0.f;
    #pragma unroll
    for (int t = 0; t < 8; ++t) {
        const int i = t * 256 + tid;
        const float v = fr[i];
        F16[row * 2048 + i] = __builtin_bit_cast(u16, (f16)v);
        i8 d1, d0;
        digits256(v, 5440.0f, d1, d0);
        hi[row * 2048 + i] = d1;
        lo[row * 2048 + i] = d0;
        dot += v * u[i];
    }
    #pragma unroll
    for (int off = 32; off >= 1; off >>= 1) dot += __shfl_down(dot, off);
    if ((tid & 63) == 0) red[tid >> 6] = dot;
    __syncthreads();
    if (tid == 0) c[row] = red[0] + red[1] + red[2] + red[3];
}

// ---------------------------------------------------------------------------
// prep_k: all independent pre-passes in one launch (256 threads).
//   blocks [0,2048)      : u[row] = Wk[row,:] . bq
//   blocks [2048,4096)   : WuT transpose tile (32x32)
//   blocks [4096,20480)  : quantW(Wq)
//   blocks [20480,36864) : quantW(Wk)
// ---------------------------------------------------------------------------
__global__ __launch_bounds__(256) void prep_k(const float* __restrict__ Wk,
                                              const float* __restrict__ bq,
                                              float* __restrict__ u,
                                              const float* __restrict__ Wq,
                                              i8* __restrict__ Wqh, i8* __restrict__ Wql,
                                              i8* __restrict__ Wkh, i8* __restrict__ Wkl,
                                              const float* __restrict__ Wu,
                                              u16* __restrict__ WuT) {
    __shared__ __align__(16) float sm[32 * 33];
    const int tid = threadIdx.x;
    const int id = blockIdx.x;
    if (id < 2048) {
        // gemv: u[id] = Wk[id,:] . bq
        const float* ar = Wk + (long)id * 2048;
        float s = 0.f;
        #pragma unroll
        for (int t = 0; t < 8; ++t) s += ar[t * 256 + tid] * bq[t * 256 + tid];
        #pragma unroll
        for (int off = 32; off >= 1; off >>= 1) s += __shfl_down(s, off);
        if ((tid & 63) == 0) sm[tid >> 6] = s;
        __syncthreads();
        if (tid == 0) u[id] = sm[0] + sm[1] + sm[2] + sm[3];
    } else if (id < 4096) {
        // WuT: Wu [2048][1024] -> WuT [1024][2048] fp16
        const int w  = id - 2048;
        const int bx = (w & 31) * 32;   // col tile of Wu
        const int by = (w >> 5) * 32;   // row tile of Wu
        const int lx = tid & 31, ly = tid >> 5;
        float (*t)[33] = (float (*)[33])sm;
        #pragma unroll
        for (int dy = 0; dy < 32; dy += 8)
            t[ly + dy][lx] = Wu[(long)(by + ly + dy) * 1024 + bx + lx];
        __syncthreads();
        #pragma unroll
        for (int dy = 0; dy < 32; dy += 8)
            WuT[(long)(bx + ly + dy) * 2048 + by + lx] =
                __builtin_bit_cast(u16, (f16)t[lx][ly + dy]);
    } else {
        long j = (long)id - 4096;       // 0..32767 block-units of 256 elems
        const float* src;
        i8 *dh, *dl;
        if (j < 16384) { src = Wq; dh = Wqh; dl = Wql; }
        else           { j -= 16384; src = Wk; dh = Wkh; dl = Wkl; }
        const long i = j * 256 + tid;   // < 4194304
        i8 d1, d0;
        digits256(src[i], 261120.0f, d1, d0);
        dh[i] = d1;
        dl[i] = d0;
    }
}

// ---------------------------------------------------------------------------
// fused_qfc_mt (256 threads): Mt = Wk @ Wq^T (blocks 0..255, launched first -
// on the critical path to S) packed with quantFc (blocks 256..9471, BW-bound).
// ---------------------------------------------------------------------------
__global__ __launch_bounds__(256, 2) void fused_qfc_mt(
    const float* __restrict__ F, const float* __restrict__ u,
    u16* __restrict__ F16, i8* __restrict__ Fh, i8* __restrict__ Fl,
    float* __restrict__ c,
    const i8* __restrict__ Wqh, const i8* __restrict__ Wql,
    const i8* __restrict__ Wkh, const i8* __restrict__ Wkl,
    i8* __restrict__ Mth, i8* __restrict__ Mtl) {
    __shared__ __align__(16) i8 lds[2][32768];
    const int b = blockIdx.x;
    if (b < 256) {
        gemm_i8_body<0>(&lds[0][0], b & 15, b >> 4, 0,
                        Wkh, Wkl, Wqh, Wql, Mth, Mtl, nullptr,
                        3.8296569e-06f, 2048, 2048, 0L, 0L, 0L);
    } else {
        quantFc_body((long)b - 256, (float*)&lds[0][0], F, u, F16, Fh, Fl, c);
    }
}

// ---------------------------------------------------------------------------
// fused_sv (256 threads): S = F @ Mt^T (bx<16) packed with v = F16 @ WuT^T
// -> vT (bx>=16).  Grid (24, 72): v blocks fill S's scheduling tail.
// ---------------------------------------------------------------------------
__global__ __launch_bounds__(256, 2) void fused_sv(
    const i8* __restrict__ Fh, const i8* __restrict__ Fl,
    const i8* __restrict__ Mth, const i8* __restrict__ Mtl,
    i8* __restrict__ Sh, i8* __restrict__ Sl,
    const u16* __restrict__ F16, const u16* __restrict__ WuT,
    u16* __restrict__ vT) {
    __shared__ __align__(16) i8 lds[2][32768];
    const int bx = blockIdx.x, by = blockIdx.y;
    if (bx < 16) {
        gemm_i8_body<0>(&lds[0][0], bx, by, 0,
                        Fh, Fl, Mth, Mtl, Sh, Sl, nullptr,
                        3.8296569e-06f, 2048, 2048, 0L, 0L, 0L);
    } else {
        gemm_f16_body<2>(&lds[0][0], bx - 16, by, 0,
                         F16, WuT, vT, nullptr, nullptr,
                         1024, 2048, 0L, 0L, 0L);
    }
}

// ---------------------------------------------------------------------------
// Standalone GEMM wrappers (adj and out; keep XCD/L2 tile swizzle).
// ---------------------------------------------------------------------------
template <int EPI>
__global__ __launch_bounds__(256, 2) void gemm_i8_k(
    const i8* __restrict__ Ah, const i8* __restrict__ Al,
    const i8* __restrict__ Bh, const i8* __restrict__ Bl,
    i8* __restrict__ Qh, i8* __restrict__ Ql, float* __restrict__ Cf,
    float oscale, int N, int K, long strA, long strB, long strC) {
    __shared__ __align__(16) i8 lds[2][32768];
    int tx, ty;
    tile_swizzle(tx, ty);
    gemm_i8_body<EPI>(&lds[0][0], tx, ty, blockIdx.z,
                      Ah, Al, Bh, Bl, Qh, Ql, Cf, oscale, N, K, strA, strB, strC);
}

template <int EPI>
__global__ __launch_bounds__(256, 3) void gemm_f16_k(
    const u16* __restrict__ A, const u16* __restrict__ B,
    u16* __restrict__ Ch, float* __restrict__ Cf,
    const float* __restrict__ bias,
    int N, int K, long strA, long strB, long strC) {
    __shared__ __align__(16) i8 lds[2][16384];
    int tx, ty;
    tile_swizzle(tx, ty);
    gemm_f16_body<EPI>(&lds[0][0], tx, ty, blockIdx.z,
                       A, B, Ch, Cf, bias, N, K, strA, strB, strC);
}

// ---------------------------------------------------------------------------
// Row softmax over 2304 cols with per-column bias c[m]; fp32 in, fp16 out.
// ---------------------------------------------------------------------------
__global__ __launch_bounds__(256) void softmax_k(const float* __restrict__ adj,
                                                 const float* __restrict__ c,
                                                 u16* __restrict__ P) {
    const int n = 2304;
    const int row = blockIdx.x, b = blockIdx.y;
    const int tid = threadIdx.x;
    const float* ar = adj + ((long)b * n + row) * (long)n;
    const float* cb = c + (long)b * n;
    u16* pr = P + ((long)b * n + row) * (long)n;

    float v[9];
    float mx = -3.0e38f;
    #pragma unroll
    for (int t = 0; t < 9; ++t) {
        const int i = t * 256 + tid;
        const float x = ar[i] + cb[i];
        v[t] = x;
        mx = fmaxf(mx, x);
    }
    #pragma unroll
    for (int off = 32; off >= 1; off >>= 1) mx = fmaxf(mx, __shfl_down(mx, off));
    __shared__ float red[4];
    if ((tid & 63) == 0) red[tid >> 6] = mx;
    __syncthreads();
    mx = fmaxf(fmaxf(red[0], red[1]), fmaxf(red[2], red[3]));

    float s = 0.f;
    #pragma unroll
    for (int t = 0; t < 9; ++t) {
        const float e = __expf(v[t] - mx);
        v[t] = e;
        s += e;
    }
    #pragma unroll
    for (int off = 32; off >= 1; off >>= 1) s += __shfl_down(s, off);
    __shared__ float red2[4];
    if ((tid & 63) == 0) red2[tid >> 6] = s;
    __syncthreads();
    s = red2[0] + red2[1] + red2[2] + red2[3];
    const float inv = 1.0f / s;
    #pragma unroll
    for (int t = 0; t < 9; ++t)
        pr[t * 256 + tid] = __builtin_bit_cast(u16, (f16)(v[t] * inv));
}

// ---------------------------------------------------------------------------
// Host launch
// ---------------------------------------------------------------------------
extern "C" void kernel_launch(void* const* d_in, const int* in_sizes, int n_in,
                              void* d_out, int out_size, void* d_ws, size_t ws_size,
                              hipStream_t stream) {
    (void)in_sizes; (void)n_in; (void)out_size; (void)ws_size;
    const float* F  = (const float*)d_in[0];  // [9216, 2048]
    const float* Wq = (const float*)d_in[1];  // [2048,2048]
    const float* bq = (const float*)d_in[2];  // [2048]
    const float* Wk = (const float*)d_in[3];  // [2048,2048]
    // d_in[4] (bk) drops out: row-constant under softmax.
    const float* Wu = (const float*)d_in[5];  // [2048,1024]
    const float* bu = (const float*)d_in[6];  // [1024]
    float* out = (float*)d_out;               // [9216, 1024]

    char* ws = (char*)d_ws;
    const long o_F16  = 0L;                      // 37748736
    const long o_Fh8  = 37748736L;
    const long o_Fl8  = 56623104L;
    const long o_Sh8  = 75497472L;
    const long o_Sl8  = 94371840L;
    const long o_adj  = 113246208L;              // 84934656
    const long o_P    = 198180864L;              // 42467328
    const long o_vT   = 240648192L;
    const long o_WuT  = 259522560L;
    const long o_Wqh  = 263716864L;
    const long o_Wql  = 267911168L;
    const long o_Wkh  = 272105472L;
    const long o_Wkl  = 276299776L;
    const long o_Mth  = 280494080L;
    const long o_Mtl  = 284688384L;
    const long o_u    = 288882688L;
    const long o_c    = 288890880L;

    u16* F16 = (u16*)(ws + o_F16);
    i8*  Fh8 = (i8*)(ws + o_Fh8);   i8* Fl8 = (i8*)(ws + o_Fl8);
    i8*  Sh8 = (i8*)(ws + o_Sh8);   i8* Sl8 = (i8*)(ws + o_Sl8);
    float* adj = (float*)(ws + o_adj);
    u16* P   = (u16*)(ws + o_P);
    u16* vT  = (u16*)(ws + o_vT);
    u16* WuT = (u16*)(ws + o_WuT);
    i8*  Wqh = (i8*)(ws + o_Wqh);   i8* Wql = (i8*)(ws + o_Wql);
    i8*  Wkh = (i8*)(ws + o_Wkh);   i8* Wkl = (i8*)(ws + o_Wkl);
    i8*  Mth = (i8*)(ws + o_Mth);   i8* Mtl = (i8*)(ws + o_Mtl);
    float* u = (float*)(ws + o_u);
    float* c = (float*)(ws + o_c);

    // --- 1: all independent pre-passes (gemv + WuT + quantW(Wq) + quantW(Wk)) ---
    prep_k<<<36864, 256, 0, stream>>>(Wk, bq, u, Wq, Wqh, Wql, Wkh, Wkl, Wu, WuT);

    // --- 2: Mt = Wk @ Wq^T (256 blocks, first) + quantFc (9216 blocks) ---
    fused_qfc_mt<<<9472, 256, 0, stream>>>(F, u, F16, Fh8, Fl8, c,
                                           Wqh, Wql, Wkh, Wkl, Mth, Mtl);

    // --- 3: S = F @ Mt^T  packed with  v = F @ Wu (vT fp16 transposed) ---
    fused_sv<<<dim3(24, 72, 1), 256, 0, stream>>>(Fh8, Fl8, Mth, Mtl, Sh8, Sl8,
                                                  F16, WuT, vT);

    // --- 4: adj = S @ F^T per batch [2304x2304]; val = comb / 5440^2 ---
    gemm_i8_k<1><<<dim3(18, 18, 4), 256, 0, stream>>>(
        Sh8, Sl8, Fh8, Fl8, nullptr, nullptr, adj,
        3.3791083e-08f, 2304, 2048,
        2304L * 2048, 2304L * 2048, 2304L * 2304);

    // --- 5: P = softmax(adj + c), fp16 ---
    softmax_k<<<dim3(2304, 4, 1), 256, 0, stream>>>(adj, c, P);

    // --- 6: out = P @ v + bu, fp32 ---
    gemm_f16_k<3><<<dim3(8, 18, 4), 256, 0, stream>>>(
        P, vT, nullptr, out, bu, 1024, 2304,
        2304L * 2304, 1024L * 2304, 2304L * 1024);
}